// Round 5
// baseline (98.161 us; speedup 1.0000x reference)
//
#include <hip/hip_runtime.h>
#include <hip/hip_bf16.h>
#include <stdint.h>

#define N_NODES 100000
#define IN_DIM 256
#define OUT_DIM 128
#define DEG 16

typedef __bf16 bf16x8 __attribute__((ext_vector_type(8)));
typedef __bf16 bf16x4 __attribute__((ext_vector_type(4)));
typedef float f32x4 __attribute__((ext_vector_type(4)));

// ---------------- kernel A: Wt[j][k] = bf16(W[k][j]) ----------------
// linear coalesced read of W; scattered 2B writes (write-combined, 64KB total)
__global__ void prep_w_kernel(const float* __restrict__ W, __bf16* __restrict__ Wt) {
    const int idx = blockIdx.x * 256 + threadIdx.x;   // 0..32767
    const int k = idx >> 7;          // 0..255
    const int j = idx & 127;         // 0..127
    Wt[j * IN_DIM + k] = (__bf16)W[idx];
}

// ---------------- kernel B: XP[m][n] = bf16( sum_k X[m][k] * W[k][n] ) ----------------
// 64-row tile, K split in 2 halves with double-buffered LDS:
//   stage h0 -> bar -> { stage h1 || compute h0 } -> bar -> compute h1
// LDS [2][64][136] bf16 = 34.8KB; word offset = 68*row + 4*lg + c -> 8 lanes per
// 4-bank group on ds_read_b128 = exactly balanced, no excess conflict.
__global__ __launch_bounds__(256) void gemm_kernel(const float* __restrict__ X,
                                                   const __bf16* __restrict__ Wt,
                                                   __bf16* __restrict__ XP) {
    __shared__ __bf16 Alds[2][64][136];
    const int t = threadIdx.x;
    const int m0 = blockIdx.x * 64;

    const int lane = t & 63;
    const int wave = t >> 6;
    const int n0 = wave * 32;
    const int lr = lane & 15;   // A row / B col / D col within fragment
    const int lg = lane >> 4;   // k-subgroup / D row-group

    // staging geometry: half = 64 rows x 128 cols f32 = 2048 float4; 8 per thread
    const int srow = (t >> 5) * 8;        // base row group: flat>>5 with i*256 -> rows (i*8 + t>>5)
    const int scol = (t & 31) * 4;        // 0..124

    auto stage = [&](int h) {
        #pragma unroll
        for (int i = 0; i < 8; ++i) {
            const int row = i * 8 + (t >> 5);     // 0..63
            int grow = m0 + row;
            if (grow >= N_NODES) grow = N_NODES - 1;   // clamp; stores guarded
            float4 v = *reinterpret_cast<const float4*>(
                X + (size_t)grow * IN_DIM + h * 128 + scol);
            bf16x4 b;
            b[0] = (__bf16)v.x; b[1] = (__bf16)v.y; b[2] = (__bf16)v.z; b[3] = (__bf16)v.w;
            *reinterpret_cast<bf16x4*>(&Alds[h][row][scol]) = b;
        }
    };

    f32x4 acc[4][2] = {};
    const __bf16* bp0 = Wt + (size_t)(n0 + lr) * IN_DIM + lg * 8;
    const __bf16* bp1 = bp0 + 16 * IN_DIM;

    auto compute_half = [&](int h) {
        #pragma unroll
        for (int ks = 0; ks < 4; ++ks) {
            const int ko = ks * 32 + lg * 8;              // within-half k offset
            bf16x8 b0 = *reinterpret_cast<const bf16x8*>(bp0 + h * 128 + ks * 32);
            bf16x8 b1 = *reinterpret_cast<const bf16x8*>(bp1 + h * 128 + ks * 32);
            bf16x8 a[4];
            #pragma unroll
            for (int mi = 0; mi < 4; ++mi)
                a[mi] = *reinterpret_cast<const bf16x8*>(&Alds[h][mi * 16 + lr][ko]);
            #pragma unroll
            for (int mi = 0; mi < 4; ++mi) {
                acc[mi][0] = __builtin_amdgcn_mfma_f32_16x16x32_bf16(a[mi], b0, acc[mi][0], 0, 0, 0);
                acc[mi][1] = __builtin_amdgcn_mfma_f32_16x16x32_bf16(a[mi], b1, acc[mi][1], 0, 0, 0);
            }
        }
    };

    stage(0);
    __syncthreads();
    stage(1);            // global loads + ds_writes to buf1 (no hazard with buf0 reads)
    compute_half(0);     // overlaps with stage(1) latency
    __syncthreads();
    compute_half(1);

    // C/D layout: col = lane&15, row = (lane>>4)*4 + r
    #pragma unroll
    for (int mi = 0; mi < 4; ++mi)
        #pragma unroll
        for (int ni = 0; ni < 2; ++ni)
            #pragma unroll
            for (int r = 0; r < 4; ++r) {
                const int row = m0 + mi * 16 + lg * 4 + r;
                if (row < N_NODES) {
                    const int col = n0 + ni * 16 + lr;
                    XP[(size_t)row * OUT_DIM + col] = (__bf16)acc[mi][ni][r];
                }
            }
}

// ---------------- kernel C: fused SDDMM + attention-weighted SpMM ----------------
// 2 rows per wave, sequential compute with ALL loads hoisted: both index loads
// at t=0, then 8 gathers back-to-back; row B's gathers stay in flight (raw
// uint4) during row A's compute. group g (lane>>4) owns edges [g*4,g*4+4);
// sub-lane sl covers cols [sl*8, sl*8+8).
__global__ __launch_bounds__(256) void gat_edge_kernel(const __bf16* __restrict__ XP,
                                                       const int* __restrict__ rp,
                                                       const int* __restrict__ ci,
                                                       const float* __restrict__ attw,
                                                       float* __restrict__ out) {
    const int lane = threadIdx.x & 63;
    const int wave = threadIdx.x >> 6;
    const int rowA = blockIdx.x * 8 + wave * 2;
    const int rowB = rowA + 1;
    const int g = lane >> 4;
    const int sl = lane & 15;

    float s = 0.f;
    #pragma unroll
    for (int h = 0; h < 8; ++h) s += attw[h];

    // hoisted loads: indices for both rows (static addresses), own-row slices
    const int4 cvA = reinterpret_cast<const int4*>(ci + (size_t)rowA * DEG)[g];
    const int4 cvB = reinterpret_cast<const int4*>(ci + (size_t)rowB * DEG)[g];
    const uint4 xvA = *reinterpret_cast<const uint4*>(XP + (size_t)rowA * OUT_DIM + sl * 8);
    const uint4 xvB = *reinterpret_cast<const uint4*>(XP + (size_t)rowB * OUT_DIM + sl * 8);

    const int cA[4] = {cvA.x, cvA.y, cvA.z, cvA.w};
    const int cB[4] = {cvB.x, cvB.y, cvB.z, cvB.w};

    // issue all 8 gathers (A first so vmcnt retires them first)
    uint4 dvA[4], dvB[4];
    #pragma unroll
    for (int j = 0; j < 4; ++j)
        dvA[j] = *reinterpret_cast<const uint4*>(XP + (size_t)cA[j] * OUT_DIM + sl * 8);
    #pragma unroll
    for (int j = 0; j < 4; ++j)
        dvB[j] = *reinterpret_cast<const uint4*>(XP + (size_t)cB[j] * OUT_DIM + sl * 8);

    // ---- row A compute ----
    {
        float x[8];
        const uint32_t* xw = reinterpret_cast<const uint32_t*>(&xvA);
        #pragma unroll
        for (int i = 0; i < 4; ++i) {
            x[2 * i]     = __uint_as_float(xw[i] << 16);
            x[2 * i + 1] = __uint_as_float(xw[i] & 0xffff0000u);
        }
        float d[4][8];
        #pragma unroll
        for (int j = 0; j < 4; ++j) {
            const uint32_t* dw = reinterpret_cast<const uint32_t*>(&dvA[j]);
            #pragma unroll
            for (int i = 0; i < 4; ++i) {
                d[j][2 * i]     = __uint_as_float(dw[i] << 16);
                d[j][2 * i + 1] = __uint_as_float(dw[i] & 0xffff0000u);
            }
        }
        float p[4];
        #pragma unroll
        for (int j = 0; j < 4; ++j) {
            float t0 = 0.f;
            #pragma unroll
            for (int i = 0; i < 8; ++i) t0 += x[i] * d[j][i];
            p[j] = t0;
        }
        #pragma unroll
        for (int off = 1; off <= 8; off <<= 1) {
            #pragma unroll
            for (int j = 0; j < 4; ++j) p[j] += __shfl_xor(p[j], off);
        }
        float acc[8] = {};
        #pragma unroll
        for (int j = 0; j < 4; ++j) {
            const float att = p[j] * s;
            #pragma unroll
            for (int i = 0; i < 8; ++i) acc[i] += att * d[j][i];
        }
        #pragma unroll
        for (int off = 16; off <= 32; off <<= 1) {
            #pragma unroll
            for (int i = 0; i < 8; ++i) acc[i] += __shfl_xor(acc[i], off);
        }
        if (g == 0) {
            float4 o0, o1;
            o0.x = acc[0]; o0.y = acc[1]; o0.z = acc[2]; o0.w = acc[3];
            o1.x = acc[4]; o1.y = acc[5]; o1.z = acc[6]; o1.w = acc[7];
            float* dst = out + (size_t)rowA * OUT_DIM + sl * 8;
            *reinterpret_cast<float4*>(dst) = o0;
            *reinterpret_cast<float4*>(dst + 4) = o1;
        }
    }

    // ---- row B compute ----
    {
        float x[8];
        const uint32_t* xw = reinterpret_cast<const uint32_t*>(&xvB);
        #pragma unroll
        for (int i = 0; i < 4; ++i) {
            x[2 * i]     = __uint_as_float(xw[i] << 16);
            x[2 * i + 1] = __uint_as_float(xw[i] & 0xffff0000u);
        }
        float d[4][8];
        #pragma unroll
        for (int j = 0; j < 4; ++j) {
            const uint32_t* dw = reinterpret_cast<const uint32_t*>(&dvB[j]);
            #pragma unroll
            for (int i = 0; i < 4; ++i) {
                d[j][2 * i]     = __uint_as_float(dw[i] << 16);
                d[j][2 * i + 1] = __uint_as_float(dw[i] & 0xffff0000u);
            }
        }
        float p[4];
        #pragma unroll
        for (int j = 0; j < 4; ++j) {
            float t0 = 0.f;
            #pragma unroll
            for (int i = 0; i < 8; ++i) t0 += x[i] * d[j][i];
            p[j] = t0;
        }
        #pragma unroll
        for (int off = 1; off <= 8; off <<= 1) {
            #pragma unroll
            for (int j = 0; j < 4; ++j) p[j] += __shfl_xor(p[j], off);
        }
        float acc[8] = {};
        #pragma unroll
        for (int j = 0; j < 4; ++j) {
            const float att = p[j] * s;
            #pragma unroll
            for (int i = 0; i < 8; ++i) acc[i] += att * d[j][i];
        }
        #pragma unroll
        for (int off = 16; off <= 32; off <<= 1) {
            #pragma unroll
            for (int i = 0; i < 8; ++i) acc[i] += __shfl_xor(acc[i], off);
        }
        if (g == 0) {
            float4 o0, o1;
            o0.x = acc[0]; o0.y = acc[1]; o0.z = acc[2]; o0.w = acc[3];
            o1.x = acc[4]; o1.y = acc[5]; o1.z = acc[6]; o1.w = acc[7];
            float* dst = out + (size_t)rowB * OUT_DIM + sl * 8;
            *reinterpret_cast<float4*>(dst) = o0;
            *reinterpret_cast<float4*>(dst + 4) = o1;
        }
    }
}

// ---------------- launch ----------------
extern "C" void kernel_launch(void* const* d_in, const int* in_sizes, int n_in,
                              void* d_out, int out_size, void* d_ws, size_t ws_size,
                              hipStream_t stream) {
    const float* X    = (const float*)d_in[0];
    const float* W    = (const float*)d_in[1];
    const float* attw = (const float*)d_in[2];
    const int*   rp   = (const int*)d_in[3];
    const int*   ci   = (const int*)d_in[4];
    float* out = (float*)d_out;

    __bf16* XP = (__bf16*)d_ws;
    __bf16* Wt = (__bf16*)((char*)d_ws + (size_t)N_NODES * OUT_DIM * 2);

    prep_w_kernel<<<(IN_DIM * OUT_DIM) / 256, 256, 0, stream>>>(W, Wt);
    gemm_kernel<<<(N_NODES + 63) / 64, 256, 0, stream>>>(X, Wt, XP);
    gat_edge_kernel<<<N_NODES / 8, 256, 0, stream>>>(XP, rp, ci, attw, out);
}

// Round 6
// 96.865 us; speedup vs baseline: 1.0134x; 1.0134x over previous
//
#include <hip/hip_runtime.h>
#include <hip/hip_bf16.h>
#include <stdint.h>

#define N_NODES 100000
#define IN_DIM 256
#define OUT_DIM 128
#define DEG 16

typedef __bf16 bf16x8 __attribute__((ext_vector_type(8)));
typedef __bf16 bf16x4 __attribute__((ext_vector_type(4)));
typedef float f32x4 __attribute__((ext_vector_type(4)));
typedef float f32x2 __attribute__((ext_vector_type(2)));

// ---------------- kernel A: Wt[j][k] = bf16(W[k][j]) ----------------
__global__ void prep_w_kernel(const float* __restrict__ W, __bf16* __restrict__ Wt) {
    const int idx = blockIdx.x * 256 + threadIdx.x;   // 0..32767
    const int k = idx >> 7;          // 0..255
    const int j = idx & 127;         // 0..127
    Wt[j * IN_DIM + k] = (__bf16)W[idx];
}

// ---------------- kernel B: XP[m][n] = bf16( sum_k X[m][k] * W[k][n] ) ----------------
// 64-row tile, K split in 2 halves with double-buffered LDS.
__global__ __launch_bounds__(256) void gemm_kernel(const float* __restrict__ X,
                                                   const __bf16* __restrict__ Wt,
                                                   __bf16* __restrict__ XP) {
    __shared__ __bf16 Alds[2][64][136];
    const int t = threadIdx.x;
    const int m0 = blockIdx.x * 64;

    const int lane = t & 63;
    const int wave = t >> 6;
    const int n0 = wave * 32;
    const int lr = lane & 15;
    const int lg = lane >> 4;

    const int scol = (t & 31) * 4;

    auto stage = [&](int h) {
        #pragma unroll
        for (int i = 0; i < 8; ++i) {
            const int row = i * 8 + (t >> 5);
            int grow = m0 + row;
            if (grow >= N_NODES) grow = N_NODES - 1;
            float4 v = *reinterpret_cast<const float4*>(
                X + (size_t)grow * IN_DIM + h * 128 + scol);
            bf16x4 b;
            b[0] = (__bf16)v.x; b[1] = (__bf16)v.y; b[2] = (__bf16)v.z; b[3] = (__bf16)v.w;
            *reinterpret_cast<bf16x4*>(&Alds[h][row][scol]) = b;
        }
    };

    f32x4 acc[4][2] = {};
    const __bf16* bp0 = Wt + (size_t)(n0 + lr) * IN_DIM + lg * 8;
    const __bf16* bp1 = bp0 + 16 * IN_DIM;

    auto compute_half = [&](int h) {
        #pragma unroll
        for (int ks = 0; ks < 4; ++ks) {
            const int ko = ks * 32 + lg * 8;
            bf16x8 b0 = *reinterpret_cast<const bf16x8*>(bp0 + h * 128 + ks * 32);
            bf16x8 b1 = *reinterpret_cast<const bf16x8*>(bp1 + h * 128 + ks * 32);
            bf16x8 a[4];
            #pragma unroll
            for (int mi = 0; mi < 4; ++mi)
                a[mi] = *reinterpret_cast<const bf16x8*>(&Alds[h][mi * 16 + lr][ko]);
            #pragma unroll
            for (int mi = 0; mi < 4; ++mi) {
                acc[mi][0] = __builtin_amdgcn_mfma_f32_16x16x32_bf16(a[mi], b0, acc[mi][0], 0, 0, 0);
                acc[mi][1] = __builtin_amdgcn_mfma_f32_16x16x32_bf16(a[mi], b1, acc[mi][1], 0, 0, 0);
            }
        }
    };

    stage(0);
    __syncthreads();
    stage(1);
    compute_half(0);
    __syncthreads();
    compute_half(1);

    #pragma unroll
    for (int mi = 0; mi < 4; ++mi)
        #pragma unroll
        for (int ni = 0; ni < 2; ++ni)
            #pragma unroll
            for (int r = 0; r < 4; ++r) {
                const int row = m0 + mi * 16 + lg * 4 + r;
                if (row < N_NODES) {
                    const int col = n0 + ni * 16 + lr;
                    XP[(size_t)row * OUT_DIM + col] = (__bf16)acc[mi][ni][r];
                }
            }
}

// ---------------- kernel C: fused SDDMM + attention-weighted SpMM ----------------
// Each 16-lane group owns ONE row (4 rows/wave, 16 rows/block). Lane sl covers
// cols [sl*8, sl*8+8). All 16 edge indices from 4 broadcast int4 loads; all 16
// gathers issued up-front (16 x 16B in flight/lane). Math in float2 so the
// backend emits v_pk_fma_f32 (2 FMA/inst). Dot-reduce: 4 independent 4-deep
// xor-shuffle chains per 4-edge batch. No cross-group reduce, full-lane store.
__global__ __launch_bounds__(256) void gat_edge_kernel(const __bf16* __restrict__ XP,
                                                       const int* __restrict__ rp,
                                                       const int* __restrict__ ci,
                                                       const float* __restrict__ attw,
                                                       float* __restrict__ out) {
    const int lane = threadIdx.x & 63;
    const int wave = threadIdx.x >> 6;
    const int g = lane >> 4;
    const int sl = lane & 15;
    const int row = blockIdx.x * 16 + wave * 4 + g;

    float s = 0.f;
    #pragma unroll
    for (int h = 0; h < 8; ++h) s += attw[h];

    // own-row slice -> f32x2[4]
    const uint4 xv = *reinterpret_cast<const uint4*>(XP + (size_t)row * OUT_DIM + sl * 8);
    f32x2 x2[4];
    {
        const uint32_t* xw = reinterpret_cast<const uint32_t*>(&xv);
        #pragma unroll
        for (int i = 0; i < 4; ++i) {
            x2[i].x = __uint_as_float(xw[i] << 16);
            x2[i].y = __uint_as_float(xw[i] & 0xffff0000u);
        }
    }

    // all 16 edge indices (redundant within group; HW merges identical addrs)
    const int4* cb = reinterpret_cast<const int4*>(ci + (size_t)row * DEG);
    const int4 i0 = cb[0], i1 = cb[1], i2 = cb[2], i3 = cb[3];
    const int c[16] = {i0.x, i0.y, i0.z, i0.w, i1.x, i1.y, i1.z, i1.w,
                       i2.x, i2.y, i2.z, i2.w, i3.x, i3.y, i3.z, i3.w};

    // issue all 16 gathers
    uint4 dv[16];
    #pragma unroll
    for (int j = 0; j < 16; ++j)
        dv[j] = *reinterpret_cast<const uint4*>(XP + (size_t)c[j] * OUT_DIM + sl * 8);

    f32x2 acc2[4] = {};

    // process in batches of 4 edges (4 independent shuffle chains = ILP 4)
    #pragma unroll
    for (int jb = 0; jb < 4; ++jb) {
        f32x2 d2[4][4];
        #pragma unroll
        for (int j = 0; j < 4; ++j) {
            const uint32_t* dw = reinterpret_cast<const uint32_t*>(&dv[jb * 4 + j]);
            #pragma unroll
            for (int i = 0; i < 4; ++i) {
                d2[j][i].x = __uint_as_float(dw[i] << 16);
                d2[j][i].y = __uint_as_float(dw[i] & 0xffff0000u);
            }
        }
        float p[4];
        #pragma unroll
        for (int j = 0; j < 4; ++j) {
            f32x2 t = x2[0] * d2[j][0];
            #pragma unroll
            for (int i = 1; i < 4; ++i) t += x2[i] * d2[j][i];
            p[j] = t.x + t.y;
        }
        #pragma unroll
        for (int off = 1; off <= 8; off <<= 1) {
            #pragma unroll
            for (int j = 0; j < 4; ++j) p[j] += __shfl_xor(p[j], off);
        }
        #pragma unroll
        for (int j = 0; j < 4; ++j) {
            const float att = p[j] * s;
            f32x2 a2; a2.x = att; a2.y = att;
            #pragma unroll
            for (int i = 0; i < 4; ++i) acc2[i] += a2 * d2[j][i];
        }
    }

    float4 o0, o1;
    o0.x = acc2[0].x; o0.y = acc2[0].y; o0.z = acc2[1].x; o0.w = acc2[1].y;
    o1.x = acc2[2].x; o1.y = acc2[2].y; o1.z = acc2[3].x; o1.w = acc2[3].y;
    float* dst = out + (size_t)row * OUT_DIM + sl * 8;
    *reinterpret_cast<float4*>(dst) = o0;
    *reinterpret_cast<float4*>(dst + 4) = o1;
}

// ---------------- launch ----------------
extern "C" void kernel_launch(void* const* d_in, const int* in_sizes, int n_in,
                              void* d_out, int out_size, void* d_ws, size_t ws_size,
                              hipStream_t stream) {
    const float* X    = (const float*)d_in[0];
    const float* W    = (const float*)d_in[1];
    const float* attw = (const float*)d_in[2];
    const int*   rp   = (const int*)d_in[3];
    const int*   ci   = (const int*)d_in[4];
    float* out = (float*)d_out;

    __bf16* XP = (__bf16*)d_ws;
    __bf16* Wt = (__bf16*)((char*)d_ws + (size_t)N_NODES * OUT_DIM * 2);

    prep_w_kernel<<<(IN_DIM * OUT_DIM) / 256, 256, 0, stream>>>(W, Wt);
    gemm_kernel<<<(N_NODES + 63) / 64, 256, 0, stream>>>(X, Wt, XP);
    gat_edge_kernel<<<N_NODES / 16, 256, 0, stream>>>(XP, rp, ci, attw, out);
}

// Round 7
// 96.173 us; speedup vs baseline: 1.0207x; 1.0072x over previous
//
#include <hip/hip_runtime.h>
#include <hip/hip_bf16.h>
#include <stdint.h>

#define N_NODES 100000
#define IN_DIM 256
#define OUT_DIM 128
#define DEG 16

typedef __bf16 bf16x8 __attribute__((ext_vector_type(8)));
typedef __bf16 bf16x4 __attribute__((ext_vector_type(4)));
typedef float f32x4 __attribute__((ext_vector_type(4)));

// ---------------- kernel A: Wt[j][k] = bf16(W[k][j]) ----------------
__global__ void prep_w_kernel(const float* __restrict__ W, __bf16* __restrict__ Wt) {
    const int idx = blockIdx.x * 256 + threadIdx.x;   // 0..32767
    const int k = idx >> 7;          // 0..255
    const int j = idx & 127;         // 0..127
    Wt[j * IN_DIM + k] = (__bf16)W[idx];
}

// ---------------- kernel B: XP[m][n] = bf16( sum_k X[m][k] * W[k][n] ) ----------------
// 64-row tile, single-shot staging (f32->bf16, linear-coalesced 1KB/wave-instr),
// MFMA compute, then LDS-funneled epilogue: acc -> Clds (overlaid on staging
// buffer) -> contiguous 16B/lane global stores (wave stores 4 rows = 1KB/instr).
__global__ __launch_bounds__(256) void gemm_kernel(const float* __restrict__ X,
                                                   const __bf16* __restrict__ Wt,
                                                   __bf16* __restrict__ XP) {
    __shared__ __bf16 smem[64 * 264];          // 33.8KB, staging + epilogue overlay
    const int t = threadIdx.x;
    const int m0 = blockIdx.x * 64;

    // ---- stage 64 rows x 256 cols f32 -> bf16 LDS ----
    #pragma unroll
    for (int i = 0; i < 16; ++i) {
        const int flat = i * 256 + t;       // 0..4095
        const int row  = flat >> 6;         // 0..63
        const int col  = (flat & 63) * 4;   // 0..252
        int grow = m0 + row;
        if (grow >= N_NODES) grow = N_NODES - 1;   // clamp; stores are guarded
        float4 v = *reinterpret_cast<const float4*>(X + (size_t)grow * IN_DIM + col);
        bf16x4 b;
        b[0] = (__bf16)v.x; b[1] = (__bf16)v.y; b[2] = (__bf16)v.z; b[3] = (__bf16)v.w;
        *reinterpret_cast<bf16x4*>(&smem[row * 264 + col]) = b;
    }
    __syncthreads();

    const int lane = t & 63;
    const int wave = t >> 6;
    const int n0 = wave * 32;
    const int lr = lane & 15;   // A row / B col / D col within fragment
    const int lg = lane >> 4;   // k-subgroup / D row-group

    f32x4 acc[4][2] = {};
    const __bf16* bp0 = Wt + (size_t)(n0 + lr) * IN_DIM + lg * 8;
    const __bf16* bp1 = bp0 + 16 * IN_DIM;

    #pragma unroll
    for (int ks = 0; ks < 8; ++ks) {
        const int ko = ks * 32 + lg * 8;
        bf16x8 b0 = *reinterpret_cast<const bf16x8*>(bp0 + ks * 32);
        bf16x8 b1 = *reinterpret_cast<const bf16x8*>(bp1 + ks * 32);
        bf16x8 a[4];
        #pragma unroll
        for (int mi = 0; mi < 4; ++mi)
            a[mi] = *reinterpret_cast<const bf16x8*>(&smem[(mi * 16 + lr) * 264 + ko]);
        #pragma unroll
        for (int mi = 0; mi < 4; ++mi) {
            acc[mi][0] = __builtin_amdgcn_mfma_f32_16x16x32_bf16(a[mi], b0, acc[mi][0], 0, 0, 0);
            acc[mi][1] = __builtin_amdgcn_mfma_f32_16x16x32_bf16(a[mi], b1, acc[mi][1], 0, 0, 0);
        }
    }

    // ---- epilogue: acc -> LDS (row stride 132) -> coalesced global stores ----
    __syncthreads();   // staging reads done before overwrite
    #pragma unroll
    for (int mi = 0; mi < 4; ++mi)
        #pragma unroll
        for (int ni = 0; ni < 2; ++ni)
            #pragma unroll
            for (int r = 0; r < 4; ++r) {
                const int row = mi * 16 + lg * 4 + r;          // 0..63
                const int col = n0 + ni * 16 + lr;             // 0..127
                smem[row * 132 + col] = (__bf16)acc[mi][ni][r];
            }
    __syncthreads();
    // thread t stores 8 bf16 (16B): flat = t*8 per pass; 2 passes cover 64x128
    #pragma unroll
    for (int pass = 0; pass < 4; ++pass) {
        const int flat = pass * 2048 + t * 8;      // 0..8184
        const int row  = flat >> 7;                // 0..63
        const int col  = flat & 127;
        const int grow = m0 + row;
        if (grow < N_NODES) {
            bf16x8 v;
            #pragma unroll
            for (int i = 0; i < 8; ++i) v[i] = smem[row * 132 + col + i];
            *reinterpret_cast<bf16x8*>(XP + (size_t)grow * OUT_DIM + col) = v;
        }
    }
}

// ---------------- kernel C: fused SDDMM + attention-weighted SpMM ----------------
// Round-2 structure (best): one wave per row; 4 groups of 16 lanes; group g owns
// edges [g*4, g*4+4); lane sl covers cols [sl*8, sl*8+8).
__global__ __launch_bounds__(256) void gat_edge_kernel(const __bf16* __restrict__ XP,
                                                       const int* __restrict__ rp,
                                                       const int* __restrict__ ci,
                                                       const float* __restrict__ attw,
                                                       float* __restrict__ out) {
    const int lane = threadIdx.x & 63;
    const int row = blockIdx.x * 4 + (threadIdx.x >> 6);
    const int g = lane >> 4;
    const int sl = lane & 15;

    float s = 0.f;
    #pragma unroll
    for (int h = 0; h < 8; ++h) s += attw[h];

    float x[8];
    {
        uint4 xv = *reinterpret_cast<const uint4*>(XP + (size_t)row * OUT_DIM + sl * 8);
        const uint32_t* xw = reinterpret_cast<const uint32_t*>(&xv);
        #pragma unroll
        for (int i = 0; i < 4; ++i) {
            x[2 * i]     = __uint_as_float(xw[i] << 16);
            x[2 * i + 1] = __uint_as_float(xw[i] & 0xffff0000u);
        }
    }

    const int4 cv = reinterpret_cast<const int4*>(ci + (size_t)row * DEG)[g];
    const int c[4] = {cv.x, cv.y, cv.z, cv.w};

    uint4 dvu[4];
    #pragma unroll
    for (int j = 0; j < 4; ++j)
        dvu[j] = *reinterpret_cast<const uint4*>(XP + (size_t)c[j] * OUT_DIM + sl * 8);

    float d[4][8];
    #pragma unroll
    for (int j = 0; j < 4; ++j) {
        const uint32_t* dw = reinterpret_cast<const uint32_t*>(&dvu[j]);
        #pragma unroll
        for (int i = 0; i < 4; ++i) {
            d[j][2 * i]     = __uint_as_float(dw[i] << 16);
            d[j][2 * i + 1] = __uint_as_float(dw[i] & 0xffff0000u);
        }
    }

    float p[4];
    #pragma unroll
    for (int j = 0; j < 4; ++j) {
        float t0 = 0.f;
        #pragma unroll
        for (int i = 0; i < 8; ++i) t0 += x[i] * d[j][i];
        p[j] = t0;
    }
    #pragma unroll
    for (int off = 1; off <= 8; off <<= 1) {
        #pragma unroll
        for (int j = 0; j < 4; ++j) p[j] += __shfl_xor(p[j], off);
    }

    float acc[8] = {};
    #pragma unroll
    for (int j = 0; j < 4; ++j) {
        const float att = p[j] * s;
        #pragma unroll
        for (int i = 0; i < 8; ++i) acc[i] += att * d[j][i];
    }

    #pragma unroll
    for (int off = 16; off <= 32; off <<= 1) {
        #pragma unroll
        for (int i = 0; i < 8; ++i) acc[i] += __shfl_xor(acc[i], off);
    }

    if (g == 0) {
        float4 o0, o1;
        o0.x = acc[0]; o0.y = acc[1]; o0.z = acc[2]; o0.w = acc[3];
        o1.x = acc[4]; o1.y = acc[5]; o1.z = acc[6]; o1.w = acc[7];
        float* dst = out + (size_t)row * OUT_DIM + sl * 8;
        *reinterpret_cast<float4*>(dst) = o0;
        *reinterpret_cast<float4*>(dst + 4) = o1;
    }
}

// ---------------- launch ----------------
extern "C" void kernel_launch(void* const* d_in, const int* in_sizes, int n_in,
                              void* d_out, int out_size, void* d_ws, size_t ws_size,
                              hipStream_t stream) {
    const float* X    = (const float*)d_in[0];
    const float* W    = (const float*)d_in[1];
    const float* attw = (const float*)d_in[2];
    const int*   rp   = (const int*)d_in[3];
    const int*   ci   = (const int*)d_in[4];
    float* out = (float*)d_out;

    __bf16* XP = (__bf16*)d_ws;
    __bf16* Wt = (__bf16*)((char*)d_ws + (size_t)N_NODES * OUT_DIM * 2);

    prep_w_kernel<<<(IN_DIM * OUT_DIM) / 256, 256, 0, stream>>>(W, Wt);
    gemm_kernel<<<(N_NODES + 63) / 64, 256, 0, stream>>>(X, Wt, XP);
    gat_edge_kernel<<<N_NODES / 4, 256, 0, stream>>>(XP, rp, ci, attw, out);
}

// Round 8
// 95.524 us; speedup vs baseline: 1.0276x; 1.0068x over previous
//
#include <hip/hip_runtime.h>
#include <hip/hip_bf16.h>
#include <stdint.h>

#define N_NODES 100000
#define IN_DIM 256
#define OUT_DIM 128
#define DEG 16

typedef __bf16 bf16x8 __attribute__((ext_vector_type(8)));
typedef __bf16 bf16x4 __attribute__((ext_vector_type(4)));
typedef float f32x4 __attribute__((ext_vector_type(4)));

// ---------------- kernel A: Wt[j][k] = bf16(W[k][j]) ----------------
__global__ void prep_w_kernel(const float* __restrict__ W, __bf16* __restrict__ Wt) {
    const int idx = blockIdx.x * 256 + threadIdx.x;   // 0..32767
    const int k = idx >> 7;          // 0..255
    const int j = idx & 127;         // 0..127
    Wt[j * IN_DIM + k] = (__bf16)W[idx];
}

// ---------------- kernel B: XP[m][n] = bf16( sum_k X[m][k] * W[k][n] ) ----------------
// 512 threads (8 waves), tile 64 rows x 128 cols, K=256 single shot.
// Same 33.8KB LDS as the 256-thr version -> 4 blocks/CU now carry up to 32
// waves/CU (2x resident waves, latency-bound fix). Wave w owns cols
// [w*16, w*16+16) (acc 4x1). Staging: loads split from ds_writes so all 8
// float4 loads issue back-to-back. Epilogue funnels acc through LDS for
// contiguous 16B/lane stores.
__global__ __launch_bounds__(512, 6) void gemm_kernel(const float* __restrict__ X,
                                                      const __bf16* __restrict__ Wt,
                                                      __bf16* __restrict__ XP) {
    __shared__ __bf16 smem[64 * 264];          // 33.8KB staging + epilogue overlay
    const int t = threadIdx.x;
    const int m0 = blockIdx.x * 64;

    // ---- stage 64 rows x 256 cols f32 -> bf16 LDS ----
    {
        float4 v[8];
        #pragma unroll
        for (int i = 0; i < 8; ++i) {
            const int flat = i * 512 + t;       // 0..4095
            const int row  = flat >> 6;         // 0..63
            const int col  = (flat & 63) * 4;   // 0..252
            int grow = m0 + row;
            if (grow >= N_NODES) grow = N_NODES - 1;   // clamp; stores guarded
            v[i] = *reinterpret_cast<const float4*>(X + (size_t)grow * IN_DIM + col);
        }
        #pragma unroll
        for (int i = 0; i < 8; ++i) {
            const int flat = i * 512 + t;
            const int row  = flat >> 6;
            const int col  = (flat & 63) * 4;
            bf16x4 b;
            b[0] = (__bf16)v[i].x; b[1] = (__bf16)v[i].y;
            b[2] = (__bf16)v[i].z; b[3] = (__bf16)v[i].w;
            *reinterpret_cast<bf16x4*>(&smem[row * 264 + col]) = b;
        }
    }
    __syncthreads();

    const int lane = t & 63;
    const int wave = t >> 6;          // 0..7
    const int n0 = wave * 16;
    const int lr = lane & 15;         // A row / B col / D col within fragment
    const int lg = lane >> 4;         // k-subgroup / D row-group

    f32x4 acc[4] = {};
    const __bf16* bp = Wt + (size_t)(n0 + lr) * IN_DIM + lg * 8;

    #pragma unroll
    for (int ks = 0; ks < 8; ++ks) {
        const int ko = ks * 32 + lg * 8;
        bf16x8 b0 = *reinterpret_cast<const bf16x8*>(bp + ks * 32);
        bf16x8 a[4];
        #pragma unroll
        for (int mi = 0; mi < 4; ++mi)
            a[mi] = *reinterpret_cast<const bf16x8*>(&smem[(mi * 16 + lr) * 264 + ko]);
        #pragma unroll
        for (int mi = 0; mi < 4; ++mi)
            acc[mi] = __builtin_amdgcn_mfma_f32_16x16x32_bf16(a[mi], b0, acc[mi], 0, 0, 0);
    }

    // ---- epilogue: acc -> LDS (row stride 132) -> coalesced global stores ----
    __syncthreads();   // staging reads done before overwrite
    #pragma unroll
    for (int mi = 0; mi < 4; ++mi)
        #pragma unroll
        for (int r = 0; r < 4; ++r) {
            const int row = mi * 16 + lg * 4 + r;          // 0..63
            const int col = n0 + lr;                       // 0..127
            smem[row * 132 + col] = (__bf16)acc[mi][r];
        }
    __syncthreads();
    // 64x128 bf16 = 8192 elems; 512 thr x 8 bf16 x 2 passes
    #pragma unroll
    for (int pass = 0; pass < 2; ++pass) {
        const int flat = pass * 4096 + t * 8;      // 0..8184
        const int row  = flat >> 7;                // 0..63
        const int col  = flat & 127;
        const int grow = m0 + row;
        if (grow < N_NODES) {
            bf16x8 v;
            #pragma unroll
            for (int i = 0; i < 8; ++i) v[i] = smem[row * 132 + col + i];
            *reinterpret_cast<bf16x8*>(XP + (size_t)grow * OUT_DIM + col) = v;
        }
    }
}

// ---------------- kernel C: fused SDDMM + attention-weighted SpMM ----------------
// Round-2 structure (best of 4 tested; pinned at the gather-path ceiling).
__global__ __launch_bounds__(256) void gat_edge_kernel(const __bf16* __restrict__ XP,
                                                       const int* __restrict__ rp,
                                                       const int* __restrict__ ci,
                                                       const float* __restrict__ attw,
                                                       float* __restrict__ out) {
    const int lane = threadIdx.x & 63;
    const int row = blockIdx.x * 4 + (threadIdx.x >> 6);
    const int g = lane >> 4;
    const int sl = lane & 15;

    float s = 0.f;
    #pragma unroll
    for (int h = 0; h < 8; ++h) s += attw[h];

    float x[8];
    {
        uint4 xv = *reinterpret_cast<const uint4*>(XP + (size_t)row * OUT_DIM + sl * 8);
        const uint32_t* xw = reinterpret_cast<const uint32_t*>(&xv);
        #pragma unroll
        for (int i = 0; i < 4; ++i) {
            x[2 * i]     = __uint_as_float(xw[i] << 16);
            x[2 * i + 1] = __uint_as_float(xw[i] & 0xffff0000u);
        }
    }

    const int4 cv = reinterpret_cast<const int4*>(ci + (size_t)row * DEG)[g];
    const int c[4] = {cv.x, cv.y, cv.z, cv.w};

    uint4 dvu[4];
    #pragma unroll
    for (int j = 0; j < 4; ++j)
        dvu[j] = *reinterpret_cast<const uint4*>(XP + (size_t)c[j] * OUT_DIM + sl * 8);

    float d[4][8];
    #pragma unroll
    for (int j = 0; j < 4; ++j) {
        const uint32_t* dw = reinterpret_cast<const uint32_t*>(&dvu[j]);
        #pragma unroll
        for (int i = 0; i < 4; ++i) {
            d[j][2 * i]     = __uint_as_float(dw[i] << 16);
            d[j][2 * i + 1] = __uint_as_float(dw[i] & 0xffff0000u);
        }
    }

    float p[4];
    #pragma unroll
    for (int j = 0; j < 4; ++j) {
        float t0 = 0.f;
        #pragma unroll
        for (int i = 0; i < 8; ++i) t0 += x[i] * d[j][i];
        p[j] = t0;
    }
    #pragma unroll
    for (int off = 1; off <= 8; off <<= 1) {
        #pragma unroll
        for (int j = 0; j < 4; ++j) p[j] += __shfl_xor(p[j], off);
    }

    float acc[8] = {};
    #pragma unroll
    for (int j = 0; j < 4; ++j) {
        const float att = p[j] * s;
        #pragma unroll
        for (int i = 0; i < 8; ++i) acc[i] += att * d[j][i];
    }

    #pragma unroll
    for (int off = 16; off <= 32; off <<= 1) {
        #pragma unroll
        for (int i = 0; i < 8; ++i) acc[i] += __shfl_xor(acc[i], off);
    }

    if (g == 0) {
        float4 o0, o1;
        o0.x = acc[0]; o0.y = acc[1]; o0.z = acc[2]; o0.w = acc[3];
        o1.x = acc[4]; o1.y = acc[5]; o1.z = acc[6]; o1.w = acc[7];
        float* dst = out + (size_t)row * OUT_DIM + sl * 8;
        *reinterpret_cast<float4*>(dst) = o0;
        *reinterpret_cast<float4*>(dst + 4) = o1;
    }
}

// ---------------- launch ----------------
extern "C" void kernel_launch(void* const* d_in, const int* in_sizes, int n_in,
                              void* d_out, int out_size, void* d_ws, size_t ws_size,
                              hipStream_t stream) {
    const float* X    = (const float*)d_in[0];
    const float* W    = (const float*)d_in[1];
    const float* attw = (const float*)d_in[2];
    const int*   rp   = (const int*)d_in[3];
    const int*   ci   = (const int*)d_in[4];
    float* out = (float*)d_out;

    __bf16* XP = (__bf16*)d_ws;
    __bf16* Wt = (__bf16*)((char*)d_ws + (size_t)N_NODES * OUT_DIM * 2);

    prep_w_kernel<<<(IN_DIM * OUT_DIM) / 256, 256, 0, stream>>>(W, Wt);
    gemm_kernel<<<(N_NODES + 63) / 64, 512, 0, stream>>>(X, Wt, XP);
    gat_edge_kernel<<<N_NODES / 4, 256, 0, stream>>>(XP, rp, ci, attw, out);
}